// Round 4
// baseline (249.195 us; speedup 1.0000x reference)
//
#include <hip/hip_runtime.h>
#include <stdint.h>

// ---------- types ----------
typedef __attribute__((ext_vector_type(8))) short s8v;   // 8 bf16 (4 VGPRs)
typedef __attribute__((ext_vector_type(4))) float f4v;   // MFMA accumulator

// ---------- helpers ----------
__device__ __forceinline__ unsigned short f2bf(float f) {
  unsigned u = __float_as_uint(f);
  u = u + 0x7FFFu + ((u >> 16) & 1u);   // RNE
  return (unsigned short)(u >> 16);
}
// monotone float->uint map: order(enc(a)) == order(a); 0 is below enc of any real float.
__device__ __forceinline__ unsigned encf(float f) {
  unsigned i = __float_as_uint(f);
  return (i & 0x80000000u) ? ~i : (i | 0x80000000u);
}
__device__ __forceinline__ float decf(unsigned u) {
  unsigned i = (u & 0x80000000u) ? (u & 0x7FFFFFFFu) : ~u;
  return __uint_as_float(i);
}
__device__ __forceinline__ void gload_lds16(const unsigned short* g, unsigned short* l) {
  __builtin_amdgcn_global_load_lds((const __attribute__((address_space(1))) void*)g,
                                   (__attribute__((address_space(3))) void*)l, 16, 0, 0);
}

// ---------- fused: q,a fp32->bf16; U -> Ut bf16 transposed; zero rmax/cmax + out ----------
__global__ void convert_kernel(const float4* __restrict__ q, const float4* __restrict__ a,
                               const float* __restrict__ U,
                               ushort4* __restrict__ qb, ushort4* __restrict__ ab,
                               unsigned short* __restrict__ Ut,
                               unsigned* __restrict__ rcmax, float* __restrict__ out) {
  const int bx = blockIdx.x;
  if (bx < 8192) {
    const int i = bx * 256 + threadIdx.x;
    float4 v = q[i];
    qb[i] = make_ushort4(f2bf(v.x), f2bf(v.y), f2bf(v.z), f2bf(v.w));
    float4 w = a[i];
    ab[i] = make_ushort4(f2bf(w.x), f2bf(w.y), f2bf(w.z), f2bf(w.w));
  } else if (bx < 8256) {
    // U transpose: 64 blocks x 256 thr, 4 elements each (tiny: 256 KB read)
    const int idx = (bx - 8192) * 256 + threadIdx.x;   // 0..16383
    const int n  = idx >> 6;
    const int k4 = (idx & 63) * 4;
    ushort4 o;
    o.x = f2bf(U[(k4 + 0) * 256 + n]);
    o.y = f2bf(U[(k4 + 1) * 256 + n]);
    o.z = f2bf(U[(k4 + 2) * 256 + n]);
    o.w = f2bf(U[(k4 + 3) * 256 + n]);
    *(ushort4*)&Ut[n * 256 + k4] = o;
  } else if (bx < 8320) {
    // zero rmax+cmax (64K uints): 64 blocks x 256 thr x 4
    const int idx = (bx - 8256) * 256 + threadIdx.x;   // 0..16383
    *(uint4*)&rcmax[idx * 4] = make_uint4(0u, 0u, 0u, 0u);
  } else {
    // zero out (8192 floats): 32 blocks (stream-ordered before wsum's atomics)
    out[(bx - 8320) * 256 + threadIdx.x] = 0.f;
  }
}

// ---------- fused qU-GEMM + S-max: one block per (batch, 128-row slab) ----------
// R17: phase 2 restructured — B comes from GLOBAL (L2), not LDS.
//  R16 analysis: phase-2 was LDS-pipe-bound (B re-read 4x by row-group waves =
//  256 KB/tile + 64 KB stage ≈ 3.6K cy/tile; conflict counter scaled exactly
//  with B-read count, ~12cy/b128 = m134's known throughput). Register math
//  pins the redundancy: aq<=64 VGPR under the proven 128-cap => R=4.
//  Fix: ab[b] is 1 MB/batch, L2-resident (b%8 XCD pinning) — read B fragments
//  directly global->reg. A wave-instr covers 16 rows x 64B contiguous lines;
//  de-swizzle is free (no banks in global). Removes ALL phase-2 LDS traffic,
//  staging, and vmcnt/barrier machinery; waves stream independently. One raw
//  s_barrier per tile (no waitcnt drain) keeps the 4 row-group waves aligned
//  so L1 absorbs the 4x read redundancy.
//  aq[2][8] hoist kept (R16-proven, VGPR 108, no spill).
// Phase 1 (unchanged, 2x4 grid): qU_tile[128][256] = qb[128x256] @ Ut[256x256],
//   staged K=64 slices; result -> qUs LDS, XOR-swizzled (16B chunk c ^ (row&7)).
// Grid (b, tm): linear%8 == b%8 pins each batch to one XCD L2.
__global__ __attribute__((amdgpu_flat_work_group_size(512, 512), amdgpu_waves_per_eu(2, 2)))
void fused_qu_smax(const unsigned short* __restrict__ qb,
                   const unsigned short* __restrict__ Ut,
                   const unsigned short* __restrict__ ab,
                   unsigned* __restrict__ rowmax,
                   unsigned* __restrict__ colmax) {
  extern __shared__ char smem[];
  unsigned short* qUs    = (unsigned short*)smem;             // 64 KB: qU tile
  unsigned short* Bs2    = (unsigned short*)(smem + 65536);   // 64 KB: phase-1 staging
  unsigned*       colLds = (unsigned*)(smem + 131072);        // 8 KB
  unsigned*       rowLds = (unsigned*)(smem + 139264);        // 512 B

  const int tid = threadIdx.x;
  const int b = blockIdx.x, tm = blockIdx.y;

  const int lane = tid & 63;
  const int m16  = lane & 15;
  const int quad = lane >> 4;
  const int wave = tid >> 6;          // 0..7
  const int wm   = wave >> 2;         // phase 1: 0..1 (row half)
  const int wn   = wave & 3;          // phase 1: 0..3
  const int wr32 = (wave >> 1) * 32;  // phase 2: 32-row group
  const int wc64 = (wave & 1) * 64;   // phase 2: 64-col group
  const int srow = tid >> 3;          // staging row (64/issue)
  const int scol = (((tid & 7) ^ (srow & 7))) * 8;   // swizzled source chunk

  #pragma unroll
  for (int i = 0; i < 4; ++i) colLds[i * 512 + tid] = 0u;
  if (tid < 128) rowLds[tid] = 0u;

  // ================= phase 1: qU tile -> LDS (single pass) =================
  const unsigned short* Aq = qb + ((long)b * 2048 + tm * 128) * 256;
  unsigned short* S1 = Bs2;            // 16 KB: A 128x64
  unsigned short* S2 = Bs2 + 8192;     // 32 KB: B 256x64
  {
    f4v acc[4][4] = {};
    for (int kt = 0; kt < 4; ++kt) {
      const int k0 = kt * 64;
      __syncthreads();                 // staging region free
      #pragma unroll
      for (int i = 0; i < 2; ++i)
        gload_lds16(Aq + (long)(i * 64 + srow) * 256 + k0 + scol, &S1[i * 4096 + tid * 8]);
      #pragma unroll
      for (int i = 0; i < 4; ++i)
        gload_lds16(Ut + (long)(i * 64 + srow) * 256 + k0 + scol, &S2[i * 4096 + tid * 8]);
      __syncthreads();                 // staging complete
      #pragma unroll
      for (int kk = 0; kk < 2; ++kk) {
        const int cs = ((kk * 4 + quad) ^ (m16 & 7)) * 8;
        s8v af[4], bfv[4];
        #pragma unroll
        for (int i = 0; i < 4; ++i)
          af[i] = *(const s8v*)&S1[(wm * 64 + i * 16 + m16) * 64 + cs];
        #pragma unroll
        for (int j = 0; j < 4; ++j)
          bfv[j] = *(const s8v*)&S2[(wn * 64 + j * 16 + m16) * 64 + cs];
        #pragma unroll
        for (int i = 0; i < 4; ++i)
          #pragma unroll
          for (int j = 0; j < 4; ++j)
            acc[i][j] = __builtin_amdgcn_mfma_f32_16x16x32_bf16(af[i], bfv[j], acc[i][j], 0, 0, 0);
      }
    }
    // write acc -> qUs (row-major 256 cols, swizzled 16B chunks)
    // C/D layout: col = lane&15, row = quad*4 + reg (verified mapping)
    #pragma unroll
    for (int i = 0; i < 4; ++i)
      #pragma unroll
      for (int r = 0; r < 4; ++r) {
        const int lr = wm * 64 + i * 16 + quad * 4 + r;
        #pragma unroll
        for (int j = 0; j < 4; ++j) {
          const int col = wn * 64 + j * 16 + m16;
          const int ch = (col >> 3) ^ (lr & 7);
          qUs[lr * 256 + ch * 8 + (col & 7)] = f2bf(acc[i][j][r]);
        }
      }
  }
  __syncthreads();   // qUs complete (read-only for the rest of the kernel)

  // ================= phase 2: 16 a-tiles, B direct from L2 =================
  const unsigned short* Ab_ = ab + (long)b * 2048 * 256;

  // hoist qU A-fragments: invariant across all 16 tiles (aq[2][8] = 64 VGPRs)
  s8v aq[2][8];
  #pragma unroll
  for (int kq = 0; kq < 8; ++kq) {
    const int cs = ((kq * 4 + quad) ^ (m16 & 7)) * 8;
    aq[0][kq] = *(const s8v*)&qUs[(wr32 + m16) * 256 + cs];
    aq[1][kq] = *(const s8v*)&qUs[(wr32 + 16 + m16) * 256 + cs];
  }

  float rmx[2][4];
  #pragma unroll
  for (int i = 0; i < 2; ++i)
    #pragma unroll
    for (int r = 0; r < 4; ++r) rmx[i][r] = -3.4e38f;

  #pragma unroll 1
  for (int tb = 0; tb < 16; ++tb) {
    // raw barrier (no waitcnt drain): keeps the 4 row-group waves temporally
    // aligned so their shared B lines hit L1; no LDS hazard exists here.
    __builtin_amdgcn_s_barrier();
    f4v acc[2][4] = {};
    #pragma unroll
    for (int kq = 0; kq < 8; ++kq) {
      // lane reads 16B of a[b, tb*128 + wc64 + j*16 + m16, kq*32 + quad*8];
      // per wave-instr: 16 rows x 64B contiguous = 16 fully-used L2 lines.
      const unsigned short* gp = Ab_ + (long)(tb * 128 + wc64 + m16) * 256 + kq * 32 + quad * 8;
      const s8v b0 = *(const s8v*)&gp[0 * 16 * 256];
      const s8v b1 = *(const s8v*)&gp[1 * 16 * 256];
      const s8v b2 = *(const s8v*)&gp[2 * 16 * 256];
      const s8v b3 = *(const s8v*)&gp[3 * 16 * 256];
      acc[0][0] = __builtin_amdgcn_mfma_f32_16x16x32_bf16(aq[0][kq], b0, acc[0][0], 0, 0, 0);
      acc[1][0] = __builtin_amdgcn_mfma_f32_16x16x32_bf16(aq[1][kq], b0, acc[1][0], 0, 0, 0);
      acc[0][1] = __builtin_amdgcn_mfma_f32_16x16x32_bf16(aq[0][kq], b1, acc[0][1], 0, 0, 0);
      acc[1][1] = __builtin_amdgcn_mfma_f32_16x16x32_bf16(aq[1][kq], b1, acc[1][1], 0, 0, 0);
      acc[0][2] = __builtin_amdgcn_mfma_f32_16x16x32_bf16(aq[0][kq], b2, acc[0][2], 0, 0, 0);
      acc[1][2] = __builtin_amdgcn_mfma_f32_16x16x32_bf16(aq[1][kq], b2, acc[1][2], 0, 0, 0);
      acc[0][3] = __builtin_amdgcn_mfma_f32_16x16x32_bf16(aq[0][kq], b3, acc[0][3], 0, 0, 0);
      acc[1][3] = __builtin_amdgcn_mfma_f32_16x16x32_bf16(aq[1][kq], b3, acc[1][3], 0, 0, 0);
    }
    // rows -> running per-lane max
    #pragma unroll
    for (int i = 0; i < 2; ++i)
      #pragma unroll
      for (int r = 0; r < 4; ++r)
        rmx[i][r] = fmaxf(rmx[i][r],
          fmaxf(fmaxf(acc[i][0][r], acc[i][1][r]),
                fmaxf(acc[i][2][r], acc[i][3][r])));
    // cols -> LDS atomicMax (no barrier needed: atomics, read only at the end)
    #pragma unroll
    for (int j = 0; j < 4; ++j) {
      float v = fmaxf(fmaxf(acc[0][j][0], acc[0][j][1]),
                      fmaxf(acc[0][j][2], acc[0][j][3]));
      v = fmaxf(v, fmaxf(fmaxf(acc[1][j][0], acc[1][j][1]),
                         fmaxf(acc[1][j][2], acc[1][j][3])));
      v = fmaxf(v, __shfl_xor(v, 16));
      v = fmaxf(v, __shfl_xor(v, 32));
      if (quad == 0) atomicMax(&colLds[tb * 128 + wc64 + j * 16 + m16], encf(v));
    }
  }

  // ---- final row maxes: shuffle over m16, combine via LDS, store ----
  #pragma unroll
  for (int i = 0; i < 2; ++i)
    #pragma unroll
    for (int r = 0; r < 4; ++r) {
      float v = rmx[i][r];
      #pragma unroll
      for (int d2 = 1; d2 < 16; d2 <<= 1) v = fmaxf(v, __shfl_xor(v, d2));
      if (m16 == 0) atomicMax(&rowLds[wr32 + i * 16 + quad * 4 + r], encf(v));
    }
  __syncthreads();
  if (tid < 128)
    rowmax[(long)b * 2048 + tm * 128 + tid] = rowLds[tid];   // plain store (block owns rows)
  // ---- col maxes: one global atomic pass ----
  #pragma unroll
  for (int i = 0; i < 4; ++i)
    atomicMax(&colmax[(long)b * 2048 + i * 512 + tid], colLds[i * 512 + tid]);
}

// ---------- fused softmax + weighted sum (bf16 inputs, 16B/lane loads) ----------
__global__ void wsum_kernel(const uint4* __restrict__ qb, const uint4* __restrict__ ab,
                            const unsigned* __restrict__ rowmax, const unsigned* __restrict__ colmax,
                            float* __restrict__ out) {
  const int tid = threadIdx.x;
  const int chunk = blockIdx.x;
  const int b = blockIdx.y;
  const int z = blockIdx.z;
  const unsigned* e = z ? colmax : rowmax;
  const uint4* src = z ? ab : qb;

  __shared__ float sm[4];
  __shared__ float ss[4];
  __shared__ float wLds[128];
  __shared__ float red[256 * 8];   // 8 KB

  float x[8];
  float m = -3.4e38f;
  #pragma unroll
  for (int j = 0; j < 8; ++j) {
    x[j] = tanhf(decf(e[b * 2048 + j * 256 + tid]));
    m = fmaxf(m, x[j]);
  }
  #pragma unroll
  for (int d2 = 1; d2 < 64; d2 <<= 1) m = fmaxf(m, __shfl_xor(m, d2));
  if ((tid & 63) == 0) sm[tid >> 6] = m;
  __syncthreads();
  m = fmaxf(fmaxf(sm[0], sm[1]), fmaxf(sm[2], sm[3]));
  float s = 0.f;
  #pragma unroll
  for (int j = 0; j < 8; ++j) s += expf(x[j] - m);
  #pragma unroll
  for (int d2 = 1; d2 < 64; d2 <<= 1) s += __shfl_xor(s, d2);
  if ((tid & 63) == 0) ss[tid >> 6] = s;
  __syncthreads();
  const float inv = 1.f / (ss[0] + ss[1] + ss[2] + ss[3]);

  if (tid < 128) {
    float xv = tanhf(decf(e[b * 2048 + chunk * 128 + tid]));
    wLds[tid] = expf(xv - m) * inv;
  }
  __syncthreads();

  const int dg = tid & 31;
  const int rg = tid >> 5;       // 0..7, rows stride 8
  float acc[8] = {};
  const long rowbase = (long)b * 2048 + chunk * 128;
  for (int t = rg; t < 128; t += 8) {
    const float wgt = wLds[t];
    uint4 v = src[(rowbase + t) * 32 + dg];
    acc[0] += wgt * __uint_as_float(v.x << 16);
    acc[1] += wgt * __uint_as_float(v.x & 0xFFFF0000u);
    acc[2] += wgt * __uint_as_float(v.y << 16);
    acc[3] += wgt * __uint_as_float(v.y & 0xFFFF0000u);
    acc[4] += wgt * __uint_as_float(v.z << 16);
    acc[5] += wgt * __uint_as_float(v.z & 0xFFFF0000u);
    acc[6] += wgt * __uint_as_float(v.w << 16);
    acc[7] += wgt * __uint_as_float(v.w & 0xFFFF0000u);
  }
  #pragma unroll
  for (int k = 0; k < 8; ++k) red[tid * 8 + k] = acc[k];
  __syncthreads();
  if (tid < 32) {
    #pragma unroll
    for (int k = 0; k < 8; ++k) {
      float v = 0.f;
      #pragma unroll
      for (int g = 0; g < 8; ++g) v += red[((g << 5) | tid) * 8 + k];
      atomicAdd(&out[z * 4096 + b * 256 + tid * 8 + k], v);
    }
  }
}

// ---------- launch ----------
extern "C" void kernel_launch(void* const* d_in, const int* in_sizes, int n_in,
                              void* d_out, int out_size, void* d_ws, size_t ws_size,
                              hipStream_t stream) {
  const float* q = (const float*)d_in[0];
  const float* a = (const float*)d_in[1];
  const float* U = (const float*)d_in[2];
  float* out = (float*)d_out;

  char* w = (char*)d_ws;
  unsigned short* qb = (unsigned short*)w;                       // 16 MB
  unsigned short* ab = (unsigned short*)(w + (16ull << 20));     // 16 MB
  unsigned short* Ut = (unsigned short*)(w + (32ull << 20));     // 128 KB
  unsigned* rmax = (unsigned*)(w + (32ull << 20) + (128ull << 10));
  unsigned* cmax = rmax + 32768;

  // allow 139776 B dynamic LDS for the fused kernel (host-side, idempotent)
  constexpr int SMEM = 139776;
  hipFuncSetAttribute((const void*)fused_qu_smax,
                      hipFuncAttributeMaxDynamicSharedMemorySize, SMEM);

  // fused q/a bf16-cast + U transpose + rmax/cmax zero + out zero
  convert_kernel<<<8352, 256, 0, stream>>>((const float4*)q, (const float4*)a, U,
                                           (ushort4*)qb, (ushort4*)ab, Ut, rmax, out);

  // qU tile in LDS + S row/col maxes; grid (b, tm) -> XCD == b%8; 8 waves/block
  fused_qu_smax<<<dim3(16, 16), 512, SMEM, stream>>>(qb, Ut, ab, rmax, cmax);

  // fused softmax + weighted pooling (bf16, 16B/lane)
  wsum_kernel<<<dim3(16, 16, 2), 256, 0, stream>>>((const uint4*)qb, (const uint4*)ab,
                                                   rmax, cmax, out);
}

// Round 5
// 157.433 us; speedup vs baseline: 1.5829x; 1.5829x over previous
//
#include <hip/hip_runtime.h>
#include <stdint.h>

// ---------- types ----------
typedef __attribute__((ext_vector_type(8))) short s8v;   // 8 bf16 (4 VGPRs)
typedef __attribute__((ext_vector_type(4))) float f4v;   // MFMA accumulator

// ---------- helpers ----------
__device__ __forceinline__ unsigned short f2bf(float f) {
  unsigned u = __float_as_uint(f);
  u = u + 0x7FFFu + ((u >> 16) & 1u);   // RNE
  return (unsigned short)(u >> 16);
}
// monotone float->uint map: order(enc(a)) == order(a); 0 is below enc of any real float.
__device__ __forceinline__ unsigned encf(float f) {
  unsigned i = __float_as_uint(f);
  return (i & 0x80000000u) ? ~i : (i | 0x80000000u);
}
__device__ __forceinline__ float decf(unsigned u) {
  unsigned i = (u & 0x80000000u) ? (u & 0x7FFFFFFFu) : ~u;
  return __uint_as_float(i);
}
__device__ __forceinline__ void gload_lds16(const unsigned short* g, unsigned short* l) {
  __builtin_amdgcn_global_load_lds((const __attribute__((address_space(1))) void*)g,
                                   (__attribute__((address_space(3))) void*)l, 16, 0, 0);
}

// ---------- fused: q,a fp32->bf16; U -> Ut bf16 transposed; zero rmax/cmax + out ----------
__global__ void convert_kernel(const float4* __restrict__ q, const float4* __restrict__ a,
                               const float* __restrict__ U,
                               ushort4* __restrict__ qb, ushort4* __restrict__ ab,
                               unsigned short* __restrict__ Ut,
                               unsigned* __restrict__ rcmax, float* __restrict__ out) {
  const int bx = blockIdx.x;
  if (bx < 8192) {
    const int i = bx * 256 + threadIdx.x;
    float4 v = q[i];
    qb[i] = make_ushort4(f2bf(v.x), f2bf(v.y), f2bf(v.z), f2bf(v.w));
    float4 w = a[i];
    ab[i] = make_ushort4(f2bf(w.x), f2bf(w.y), f2bf(w.z), f2bf(w.w));
  } else if (bx < 8256) {
    // U transpose: 64 blocks x 256 thr, 4 elements each (tiny: 256 KB read)
    const int idx = (bx - 8192) * 256 + threadIdx.x;   // 0..16383
    const int n  = idx >> 6;
    const int k4 = (idx & 63) * 4;
    ushort4 o;
    o.x = f2bf(U[(k4 + 0) * 256 + n]);
    o.y = f2bf(U[(k4 + 1) * 256 + n]);
    o.z = f2bf(U[(k4 + 2) * 256 + n]);
    o.w = f2bf(U[(k4 + 3) * 256 + n]);
    *(ushort4*)&Ut[n * 256 + k4] = o;
  } else if (bx < 8320) {
    // zero rmax+cmax (64K uints): 64 blocks x 256 thr x 4
    const int idx = (bx - 8256) * 256 + threadIdx.x;   // 0..16383
    *(uint4*)&rcmax[idx * 4] = make_uint4(0u, 0u, 0u, 0u);
  } else {
    // zero out (8192 floats): 32 blocks (stream-ordered before wsum's atomics)
    out[(bx - 8320) * 256 + threadIdx.x] = 0.f;
  }
}

// ---------- fused qU-GEMM + S-max: one block per (batch, 128-row slab) ----------
// R18: phase 2 reverted to R16's LDS-staged form (proven 53.4us; R17's
// global-direct B regressed 3x: MFMA B-frag layout = 16-line gather per load
// instr -> TA/latency bound, MfmaUtil 10%). NEW in R18: phase-1 double-buffer.
//  Phase 1 previously serialized stage -> vmcnt(0)+barrier -> compute per kt.
//  qUs (64 KB) is dead until the epilogue, so kt staging ping-pongs Bs2/qUs
//  with counted vmcnt(6) (6 gload_lds issues/kt) — same T3/T4 pattern already
//  proven in phase 2. One added __syncthreads() isolates kt3's staged reads
//  from the epilogue's qUs overwrite.
// R16 structure kept: phase-2 wave grid 4x2 (32 qU-rows x 64 a-cols/wave),
//  aq[2][8]=64 VGPR hoist (fits the demonstrated 128-VGPR allocator cap;
//  VGPR_Count=108, no scratch), double-buffered a-tile staging with vmcnt(8).
// Grid (b, tm): linear%8 == b%8 pins each batch to one XCD L2.
__global__ __attribute__((amdgpu_flat_work_group_size(512, 512), amdgpu_waves_per_eu(2, 2)))
void fused_qu_smax(const unsigned short* __restrict__ qb,
                   const unsigned short* __restrict__ Ut,
                   const unsigned short* __restrict__ ab,
                   unsigned* __restrict__ rowmax,
                   unsigned* __restrict__ colmax) {
  extern __shared__ char smem[];
  unsigned short* qUs    = (unsigned short*)smem;             // 64 KB: stage buf B, then qU tile
  unsigned short* Bs2    = (unsigned short*)(smem + 65536);   // 64 KB: stage buf A
  unsigned*       colLds = (unsigned*)(smem + 131072);        // 8 KB
  unsigned*       rowLds = (unsigned*)(smem + 139264);        // 512 B

  const int tid = threadIdx.x;
  const int b = blockIdx.x, tm = blockIdx.y;

  const int lane = tid & 63;
  const int m16  = lane & 15;
  const int quad = lane >> 4;
  const int wave = tid >> 6;          // 0..7
  const int wm   = wave >> 2;         // phase 1: 0..1 (row half)
  const int wn   = wave & 3;          // phase 1: 0..3
  const int wr32 = (wave >> 1) * 32;  // phase 2: 32-row group
  const int wc64 = (wave & 1) * 64;   // phase 2: 64-col group
  const int srow = tid >> 3;          // staging row (64/issue)
  const int scol = (((tid & 7) ^ (srow & 7))) * 8;   // swizzled source chunk

  #pragma unroll
  for (int i = 0; i < 4; ++i) colLds[i * 512 + tid] = 0u;
  if (tid < 128) rowLds[tid] = 0u;

  // ================= phase 1: qU tile -> LDS (double-buffered) =================
  // Layout inside each 48 KB staging image: A 128x64 at [0, 16KB), B(Ut) 256x64
  // at [16KB, 48KB). Buffers alternate Bs2 (kt even) / qUs (kt odd).
  const unsigned short* Aq = qb + ((long)b * 2048 + tm * 128) * 256;
  {
    f4v acc[4][4] = {};

#define STAGE1(kt, dst) do {                                                   \
    const int k0_ = (kt) * 64;                                                 \
    _Pragma("unroll")                                                          \
    for (int i_ = 0; i_ < 2; ++i_)                                             \
      gload_lds16(Aq + (long)(i_ * 64 + srow) * 256 + k0_ + scol,              \
                  &(dst)[i_ * 4096 + tid * 8]);                                \
    _Pragma("unroll")                                                          \
    for (int i_ = 0; i_ < 4; ++i_)                                             \
      gload_lds16(Ut + (long)(i_ * 64 + srow) * 256 + k0_ + scol,              \
                  &(dst)[8192 + i_ * 4096 + tid * 8]);                         \
  } while (0)

#define COMPUTE1(buf) do {                                                     \
    _Pragma("unroll")                                                          \
    for (int kk_ = 0; kk_ < 2; ++kk_) {                                        \
      const int cs_ = ((kk_ * 4 + quad) ^ (m16 & 7)) * 8;                      \
      s8v af_[4], bf_[4];                                                      \
      _Pragma("unroll")                                                        \
      for (int i_ = 0; i_ < 4; ++i_)                                           \
        af_[i_] = *(const s8v*)&(buf)[(wm * 64 + i_ * 16 + m16) * 64 + cs_];   \
      _Pragma("unroll")                                                        \
      for (int j_ = 0; j_ < 4; ++j_)                                           \
        bf_[j_] = *(const s8v*)&(buf)[8192 + (wn * 64 + j_ * 16 + m16) * 64 + cs_]; \
      _Pragma("unroll")                                                        \
      for (int i_ = 0; i_ < 4; ++i_)                                           \
        _Pragma("unroll")                                                      \
        for (int j_ = 0; j_ < 4; ++j_)                                         \
          acc[i_][j_] = __builtin_amdgcn_mfma_f32_16x16x32_bf16(af_[i_], bf_[j_], acc[i_][j_], 0, 0, 0); \
    }                                                                          \
  } while (0)

    STAGE1(0, Bs2);
    STAGE1(1, qUs);
    // kt0: 12 outstanding; vmcnt(6) -> kt0's 6 landed (in-order accounting)
    asm volatile("s_waitcnt vmcnt(6)" ::: "memory");
    __builtin_amdgcn_s_barrier();
    COMPUTE1(Bs2);
    __builtin_amdgcn_s_barrier();                      // Bs2 reads done -> restage-safe
    STAGE1(2, Bs2);
    // kt1
    asm volatile("s_waitcnt vmcnt(6)" ::: "memory");
    __builtin_amdgcn_s_barrier();
    COMPUTE1(qUs);
    __builtin_amdgcn_s_barrier();                      // qUs reads done -> restage-safe
    STAGE1(3, qUs);
    // kt2
    asm volatile("s_waitcnt vmcnt(6)" ::: "memory");
    __builtin_amdgcn_s_barrier();
    COMPUTE1(Bs2);
    // kt3 (drain)
    asm volatile("s_waitcnt vmcnt(0)" ::: "memory");
    __builtin_amdgcn_s_barrier();
    COMPUTE1(qUs);
    __syncthreads();   // ALL waves' kt3 staged reads done before epilogue rewrites qUs

    // write acc -> qUs (row-major 256 cols, swizzled 16B chunks)
    // C/D layout: col = lane&15, row = quad*4 + reg (verified mapping)
    #pragma unroll
    for (int i = 0; i < 4; ++i)
      #pragma unroll
      for (int r = 0; r < 4; ++r) {
        const int lr = wm * 64 + i * 16 + quad * 4 + r;
        #pragma unroll
        for (int j = 0; j < 4; ++j) {
          const int col = wn * 64 + j * 16 + m16;
          const int ch = (col >> 3) ^ (lr & 7);
          qUs[lr * 256 + ch * 8 + (col & 7)] = f2bf(acc[i][j][r]);
        }
      }
  }
  __syncthreads();   // qUs complete; Bs2 free for phase 2

  // ================= phase 2: 16 a-tiles vs register-resident qU =================
  const unsigned short* Ab_ = ab + (long)b * 2048 * 256;

#define STAGE_TILE(tb, dst) do {                                               \
    _Pragma("unroll")                                                          \
    for (int e_ = 0; e_ < 8; ++e_) {                                           \
      const int u_ = e_ * 512 + tid;                                           \
      const int row_ = u_ >> 5;                                                \
      const int chs_ = (u_ & 31) ^ (row_ & 7);                                 \
      gload_lds16(Ab_ + (long)((tb) * 128 + row_) * 256 + chs_ * 8,            \
                  &(dst)[u_ * 8]);                                             \
    }                                                                          \
  } while (0)

#define COMPUTE_TILE(tb, buf) do {                                             \
    f4v acc[2][4] = {};                                                        \
    _Pragma("unroll")                                                          \
    for (int kq_ = 0; kq_ < 8; ++kq_) {                                        \
      const int cs_ = ((kq_ * 4 + quad) ^ (m16 & 7)) * 8;                      \
      _Pragma("unroll")                                                        \
      for (int j_ = 0; j_ < 4; ++j_) {                                         \
        const s8v bv_ = *(const s8v*)&(buf)[(wc64 + j_ * 16 + m16) * 256 + cs_]; \
        acc[0][j_] = __builtin_amdgcn_mfma_f32_16x16x32_bf16(aq[0][kq_], bv_, acc[0][j_], 0, 0, 0); \
        acc[1][j_] = __builtin_amdgcn_mfma_f32_16x16x32_bf16(aq[1][kq_], bv_, acc[1][j_], 0, 0, 0); \
      }                                                                        \
    }                                                                          \
    _Pragma("unroll")                                                          \
    for (int i_ = 0; i_ < 2; ++i_)                                             \
      _Pragma("unroll")                                                        \
      for (int r_ = 0; r_ < 4; ++r_)                                           \
        rmx[i_][r_] = fmaxf(rmx[i_][r_],                                       \
          fmaxf(fmaxf(acc[i_][0][r_], acc[i_][1][r_]),                         \
                fmaxf(acc[i_][2][r_], acc[i_][3][r_])));                       \
    _Pragma("unroll")                                                          \
    for (int j_ = 0; j_ < 4; ++j_) {                                           \
      float v_ = fmaxf(fmaxf(acc[0][j_][0], acc[0][j_][1]),                    \
                       fmaxf(acc[0][j_][2], acc[0][j_][3]));                   \
      v_ = fmaxf(v_, fmaxf(fmaxf(acc[1][j_][0], acc[1][j_][1]),                \
                           fmaxf(acc[1][j_][2], acc[1][j_][3])));              \
      v_ = fmaxf(v_, __shfl_xor(v_, 16));                                      \
      v_ = fmaxf(v_, __shfl_xor(v_, 32));                                      \
      if (quad == 0)                                                           \
        atomicMax(&colLds[(tb) * 128 + wc64 + j_ * 16 + m16], encf(v_));       \
    }                                                                          \
  } while (0)

  // issue tile-0 staging first so the globals fly during the A-frag hoist
  STAGE_TILE(0, Bs2);

  // hoist qU A-fragments: invariant across all 16 tiles (aq[2][8] = 64 VGPRs)
  s8v aq[2][8];
  #pragma unroll
  for (int kq = 0; kq < 8; ++kq) {
    const int cs = ((kq * 4 + quad) ^ (m16 & 7)) * 8;
    aq[0][kq] = *(const s8v*)&qUs[(wr32 + m16) * 256 + cs];
    aq[1][kq] = *(const s8v*)&qUs[(wr32 + 16 + m16) * 256 + cs];
  }
  // all waves must have their qU reads DATA-RETURNED before qUs is restaged
  asm volatile("s_waitcnt lgkmcnt(0)" ::: "memory");
  __builtin_amdgcn_s_barrier();

  float rmx[2][4];
  #pragma unroll
  for (int i = 0; i < 2; ++i)
    #pragma unroll
    for (int r = 0; r < 4; ++r) rmx[i][r] = -3.4e38f;

  // double-buffered pipeline: stage(t+1) issued BEFORE compute(t); counted
  // vmcnt(8) keeps the next tile's 8 loads in flight across the barrier.
  #pragma unroll 1
  for (int t2 = 0; t2 < 8; ++t2) {
    const int te = t2 * 2;
    // ---- even tile: compute Bs2, stage te+1 -> qUs-region ----
    STAGE_TILE(te + 1, qUs);
    asm volatile("s_waitcnt vmcnt(8)" ::: "memory");   // tile te's loads landed
    __builtin_amdgcn_s_barrier();
    COMPUTE_TILE(te, Bs2);
    __builtin_amdgcn_s_barrier();                      // Bs2 reads done -> restage-safe
    // ---- odd tile: compute qUs-region, stage te+2 -> Bs2 ----
    if (te + 2 < 16) {
      STAGE_TILE(te + 2, Bs2);
      asm volatile("s_waitcnt vmcnt(8)" ::: "memory"); // tile te+1's loads landed
    } else {
      asm volatile("s_waitcnt vmcnt(0)" ::: "memory"); // drain for last tile
    }
    __builtin_amdgcn_s_barrier();
    COMPUTE_TILE(te + 1, qUs);
    __builtin_amdgcn_s_barrier();                      // qUs reads done -> restage-safe
  }

  // ---- final row maxes: shuffle over m16, combine wc-waves via LDS, store ----
  #pragma unroll
  for (int i = 0; i < 2; ++i)
    #pragma unroll
    for (int r = 0; r < 4; ++r) {
      float v = rmx[i][r];
      #pragma unroll
      for (int d2 = 1; d2 < 16; d2 <<= 1) v = fmaxf(v, __shfl_xor(v, d2));
      if (m16 == 0) atomicMax(&rowLds[wr32 + i * 16 + quad * 4 + r], encf(v));
    }
  __syncthreads();
  if (tid < 128)
    rowmax[(long)b * 2048 + tm * 128 + tid] = rowLds[tid];   // plain store (block owns rows)
  // ---- col maxes: one global atomic pass ----
  #pragma unroll
  for (int i = 0; i < 4; ++i)
    atomicMax(&colmax[(long)b * 2048 + i * 512 + tid], colLds[i * 512 + tid]);
}

// ---------- fused softmax + weighted sum (bf16 inputs, 16B/lane loads) ----------
__global__ void wsum_kernel(const uint4* __restrict__ qb, const uint4* __restrict__ ab,
                            const unsigned* __restrict__ rowmax, const unsigned* __restrict__ colmax,
                            float* __restrict__ out) {
  const int tid = threadIdx.x;
  const int chunk = blockIdx.x;
  const int b = blockIdx.y;
  const int z = blockIdx.z;
  const unsigned* e = z ? colmax : rowmax;
  const uint4* src = z ? ab : qb;

  __shared__ float sm[4];
  __shared__ float ss[4];
  __shared__ float wLds[128];
  __shared__ float red[256 * 8];   // 8 KB

  float x[8];
  float m = -3.4e38f;
  #pragma unroll
  for (int j = 0; j < 8; ++j) {
    x[j] = tanhf(decf(e[b * 2048 + j * 256 + tid]));
    m = fmaxf(m, x[j]);
  }
  #pragma unroll
  for (int d2 = 1; d2 < 64; d2 <<= 1) m = fmaxf(m, __shfl_xor(m, d2));
  if ((tid & 63) == 0) sm[tid >> 6] = m;
  __syncthreads();
  m = fmaxf(fmaxf(sm[0], sm[1]), fmaxf(sm[2], sm[3]));
  float s = 0.f;
  #pragma unroll
  for (int j = 0; j < 8; ++j) s += expf(x[j] - m);
  #pragma unroll
  for (int d2 = 1; d2 < 64; d2 <<= 1) s += __shfl_xor(s, d2);
  if ((tid & 63) == 0) ss[tid >> 6] = s;
  __syncthreads();
  const float inv = 1.f / (ss[0] + ss[1] + ss[2] + ss[3]);

  if (tid < 128) {
    float xv = tanhf(decf(e[b * 2048 + chunk * 128 + tid]));
    wLds[tid] = expf(xv - m) * inv;
  }
  __syncthreads();

  const int dg = tid & 31;
  const int rg = tid >> 5;       // 0..7, rows stride 8
  float acc[8] = {};
  const long rowbase = (long)b * 2048 + chunk * 128;
  for (int t = rg; t < 128; t += 8) {
    const float wgt = wLds[t];
    uint4 v = src[(rowbase + t) * 32 + dg];
    acc[0] += wgt * __uint_as_float(v.x << 16);
    acc[1] += wgt * __uint_as_float(v.x & 0xFFFF0000u);
    acc[2] += wgt * __uint_as_float(v.y << 16);
    acc[3] += wgt * __uint_as_float(v.y & 0xFFFF0000u);
    acc[4] += wgt * __uint_as_float(v.z << 16);
    acc[5] += wgt * __uint_as_float(v.z & 0xFFFF0000u);
    acc[6] += wgt * __uint_as_float(v.w << 16);
    acc[7] += wgt * __uint_as_float(v.w & 0xFFFF0000u);
  }
  #pragma unroll
  for (int k = 0; k < 8; ++k) red[tid * 8 + k] = acc[k];
  __syncthreads();
  if (tid < 32) {
    #pragma unroll
    for (int k = 0; k < 8; ++k) {
      float v = 0.f;
      #pragma unroll
      for (int g = 0; g < 8; ++g) v += red[((g << 5) | tid) * 8 + k];
      atomicAdd(&out[z * 4096 + b * 256 + tid * 8 + k], v);
    }
  }
}

// ---------- launch ----------
extern "C" void kernel_launch(void* const* d_in, const int* in_sizes, int n_in,
                              void* d_out, int out_size, void* d_ws, size_t ws_size,
                              hipStream_t stream) {
  const float* q = (const float*)d_in[0];
  const float* a = (const float*)d_in[1];
  const float* U = (const float*)d_in[2];
  float* out = (float*)d_out;

  char* w = (char*)d_ws;
  unsigned short* qb = (unsigned short*)w;                       // 16 MB
  unsigned short* ab = (unsigned short*)(w + (16ull << 20));     // 16 MB
  unsigned short* Ut = (unsigned short*)(w + (32ull << 20));     // 128 KB
  unsigned* rmax = (unsigned*)(w + (32ull << 20) + (128ull << 10));
  unsigned* cmax = rmax + 32768;

  // allow 139776 B dynamic LDS for the fused kernel (host-side, idempotent)
  constexpr int SMEM = 139776;
  hipFuncSetAttribute((const void*)fused_qu_smax,
                      hipFuncAttributeMaxDynamicSharedMemorySize, SMEM);

  // fused q/a bf16-cast + U transpose + rmax/cmax zero + out zero
  convert_kernel<<<8352, 256, 0, stream>>>((const float4*)q, (const float4*)a, U,
                                           (ushort4*)qb, (ushort4*)ab, Ut, rmax, out);

  // qU tile in LDS + S row/col maxes; grid (b, tm) -> XCD == b%8; 8 waves/block
  fused_qu_smax<<<dim3(16, 16), 512, SMEM, stream>>>(qb, Ut, ab, rmax, cmax);

  // fused softmax + weighted pooling (bf16, 16B/lane)
  wsum_kernel<<<dim3(16, 16, 2), 256, 0, stream>>>((const uint4*)qb, (const uint4*)ab,
                                                   rmax, cmax, out);
}

// Round 6
// 156.428 us; speedup vs baseline: 1.5930x; 1.0064x over previous
//
#include <hip/hip_runtime.h>
#include <stdint.h>

// ---------- types ----------
typedef __attribute__((ext_vector_type(8))) short s8v;   // 8 bf16 (4 VGPRs)
typedef __attribute__((ext_vector_type(4))) float f4v;   // MFMA accumulator

// ---------- helpers ----------
__device__ __forceinline__ unsigned short f2bf(float f) {
  unsigned u = __float_as_uint(f);
  u = u + 0x7FFFu + ((u >> 16) & 1u);   // RNE
  return (unsigned short)(u >> 16);
}
// monotone float->uint map: order(enc(a)) == order(a); 0 is below enc of any real float.
__device__ __forceinline__ unsigned encf(float f) {
  unsigned i = __float_as_uint(f);
  return (i & 0x80000000u) ? ~i : (i | 0x80000000u);
}
__device__ __forceinline__ float decf(unsigned u) {
  unsigned i = (u & 0x80000000u) ? (u & 0x7FFFFFFFu) : ~u;
  return __uint_as_float(i);
}
__device__ __forceinline__ void gload_lds16(const unsigned short* g, unsigned short* l) {
  __builtin_amdgcn_global_load_lds((const __attribute__((address_space(1))) void*)g,
                                   (__attribute__((address_space(3))) void*)l, 16, 0, 0);
}

// ---------- fused: q,a fp32->bf16; U -> Ut bf16 transposed; zero rmax/cmax + out ----------
__global__ void convert_kernel(const float4* __restrict__ q, const float4* __restrict__ a,
                               const float* __restrict__ U,
                               ushort4* __restrict__ qb, ushort4* __restrict__ ab,
                               unsigned short* __restrict__ Ut,
                               unsigned* __restrict__ rcmax, float* __restrict__ out) {
  const int bx = blockIdx.x;
  if (bx < 8192) {
    const int i = bx * 256 + threadIdx.x;
    float4 v = q[i];
    qb[i] = make_ushort4(f2bf(v.x), f2bf(v.y), f2bf(v.z), f2bf(v.w));
    float4 w = a[i];
    ab[i] = make_ushort4(f2bf(w.x), f2bf(w.y), f2bf(w.z), f2bf(w.w));
  } else if (bx < 8256) {
    // U transpose: 64 blocks x 256 thr, 4 elements each (tiny: 256 KB read)
    const int idx = (bx - 8192) * 256 + threadIdx.x;   // 0..16383
    const int n  = idx >> 6;
    const int k4 = (idx & 63) * 4;
    ushort4 o;
    o.x = f2bf(U[(k4 + 0) * 256 + n]);
    o.y = f2bf(U[(k4 + 1) * 256 + n]);
    o.z = f2bf(U[(k4 + 2) * 256 + n]);
    o.w = f2bf(U[(k4 + 3) * 256 + n]);
    *(ushort4*)&Ut[n * 256 + k4] = o;
  } else if (bx < 8320) {
    // zero rmax+cmax (64K uints): 64 blocks x 256 thr x 4
    const int idx = (bx - 8256) * 256 + threadIdx.x;   // 0..16383
    *(uint4*)&rcmax[idx * 4] = make_uint4(0u, 0u, 0u, 0u);
  } else {
    // zero out (8192 floats): 32 blocks (stream-ordered before wsum's atomics)
    out[(bx - 8320) * 256 + threadIdx.x] = 0.f;
  }
}

// ---------- fused qU-GEMM + S-max: one block per (batch, 128-row slab) ----------
// R19: phase 2 -> depth-3 pipeline with 64-row a-tiles (4 x 32 KB ring).
//  R18 analysis: conflict counter tracks ds_read_b128 count at ~4cy/instr in
//  EVERY round (pattern-independent) => b128's 2-accesses/bank/phase is
//  inherent, not swizzle-fixable; effective b128 ~16cy => phase-2 LDS ~31us,
//  +phase1 ~8 + tails ~= 42-45 of the measured 54 — the ~10us gap is pipeline
//  bubbles (1-phase prefetch lead, coarse barriers). Fix: 32 tiles of 64 rows,
//  ring SBUF(0..3), stage lead 3 phases, uniform vmcnt(8) mid-loop (peeled
//  vmcnt(4)/(0) tail), tiles 0/1 staged DURING phase-1 kt3+epilogue+hoist
//  (Bs2 region free after kt2). Epilogue syncs use lgkmcnt+s_barrier instead
//  of __syncthreads so they don't drain the in-flight a-tile loads.
//  Buffer map: tile t -> SBUF((t+2)&3)  (t0->S2,t1->S3 free early; t2->S0 =
//  dead qU tile after the aq hoist).
// R16 structure kept: phase-2 wave grid 4x2 -> now 4 row-groups x 2 col-groups
//  over 128x64 output chunk (j=2), aq[2][8]=64 VGPR hoist (under the proven
//  128-VGPR allocator cap), same XOR swizzle pairs.
// Grid (b, tm): linear%8 == b%8 pins each batch to one XCD L2.
__global__ __attribute__((amdgpu_flat_work_group_size(512, 512), amdgpu_waves_per_eu(2, 2)))
void fused_qu_smax(const unsigned short* __restrict__ qb,
                   const unsigned short* __restrict__ Ut,
                   const unsigned short* __restrict__ ab,
                   unsigned* __restrict__ rowmax,
                   unsigned* __restrict__ colmax) {
  extern __shared__ char smem[];
  unsigned short* qUs    = (unsigned short*)smem;             // 64 KB: ph1 stage B image, then qU tile
  unsigned short* Bs2    = (unsigned short*)(smem + 65536);   // 64 KB: ph1 stage A image
  unsigned*       colLds = (unsigned*)(smem + 131072);        // 8 KB
  unsigned*       rowLds = (unsigned*)(smem + 139264);        // 512 B
#define SBUF(k) ((unsigned short*)(smem + ((k) << 15)))       // 4 x 32 KB ring (phase 2)

  const int tid = threadIdx.x;
  const int b = blockIdx.x, tm = blockIdx.y;

  const int lane = tid & 63;
  const int m16  = lane & 15;
  const int quad = lane >> 4;
  const int wave = tid >> 6;          // 0..7
  const int wm   = wave >> 2;         // phase 1: 0..1 (row half)
  const int wn   = wave & 3;          // phase 1: 0..3
  const int wr32 = (wave >> 1) * 32;  // phase 2: 32-row group
  const int wc32 = (wave & 1) * 32;   // phase 2: 32-col group
  const int srow = tid >> 3;          // staging row (64/issue)
  const int scol = (((tid & 7) ^ (srow & 7))) * 8;   // swizzled source chunk

  #pragma unroll
  for (int i = 0; i < 4; ++i) colLds[i * 512 + tid] = 0u;
  if (tid < 128) rowLds[tid] = 0u;

  const unsigned short* Ab_ = ab + (long)b * 2048 * 256;

  // phase-2 a-tile stage: 64 rows x 256 cols bf16 = 32 KB, 4 issues/thread
#define STG64(tb, dst) do {                                                    \
    _Pragma("unroll")                                                          \
    for (int e_ = 0; e_ < 4; ++e_) {                                           \
      const int u_ = e_ * 512 + tid;        /* 16B unit: row=u>>5, chunk=u&31 */ \
      const int row_ = u_ >> 5;                                                \
      const int chs_ = (u_ & 31) ^ (row_ & 7);                                 \
      gload_lds16(Ab_ + (long)((tb) * 64 + row_) * 256 + chs_ * 8,             \
                  &(dst)[u_ * 8]);                                             \
    }                                                                          \
  } while (0)

  // ================= phase 1: qU tile -> LDS (double-buffered) =================
  const unsigned short* Aq = qb + ((long)b * 2048 + tm * 128) * 256;
  {
    f4v acc[4][4] = {};

#define STAGE1(kt, dst) do {                                                   \
    const int k0_ = (kt) * 64;                                                 \
    _Pragma("unroll")                                                          \
    for (int i_ = 0; i_ < 2; ++i_)                                             \
      gload_lds16(Aq + (long)(i_ * 64 + srow) * 256 + k0_ + scol,              \
                  &(dst)[i_ * 4096 + tid * 8]);                                \
    _Pragma("unroll")                                                          \
    for (int i_ = 0; i_ < 4; ++i_)                                             \
      gload_lds16(Ut + (long)(i_ * 64 + srow) * 256 + k0_ + scol,              \
                  &(dst)[8192 + i_ * 4096 + tid * 8]);                         \
  } while (0)

#define COMPUTE1(buf) do {                                                     \
    _Pragma("unroll")                                                          \
    for (int kk_ = 0; kk_ < 2; ++kk_) {                                        \
      const int cs_ = ((kk_ * 4 + quad) ^ (m16 & 7)) * 8;                      \
      s8v af_[4], bf_[4];                                                      \
      _Pragma("unroll")                                                        \
      for (int i_ = 0; i_ < 4; ++i_)                                           \
        af_[i_] = *(const s8v*)&(buf)[(wm * 64 + i_ * 16 + m16) * 64 + cs_];   \
      _Pragma("unroll")                                                        \
      for (int j_ = 0; j_ < 4; ++j_)                                           \
        bf_[j_] = *(const s8v*)&(buf)[8192 + (wn * 64 + j_ * 16 + m16) * 64 + cs_]; \
      _Pragma("unroll")                                                        \
      for (int i_ = 0; i_ < 4; ++i_)                                           \
        _Pragma("unroll")                                                      \
        for (int j_ = 0; j_ < 4; ++j_)                                         \
          acc[i_][j_] = __builtin_amdgcn_mfma_f32_16x16x32_bf16(af_[i_], bf_[j_], acc[i_][j_], 0, 0, 0); \
    }                                                                          \
  } while (0)

    STAGE1(0, Bs2);
    STAGE1(1, qUs);
    asm volatile("s_waitcnt vmcnt(6)" ::: "memory");   // kt0 landed
    __builtin_amdgcn_s_barrier();
    COMPUTE1(Bs2);
    __builtin_amdgcn_s_barrier();                      // Bs2 reads done -> restage-safe
    STAGE1(2, Bs2);
    asm volatile("s_waitcnt vmcnt(6)" ::: "memory");   // kt1 landed
    __builtin_amdgcn_s_barrier();
    COMPUTE1(qUs);
    __builtin_amdgcn_s_barrier();                      // qUs reads done -> restage-safe
    STAGE1(3, qUs);
    asm volatile("s_waitcnt vmcnt(6)" ::: "memory");   // kt2 landed
    __builtin_amdgcn_s_barrier();
    COMPUTE1(Bs2);                                     // kt2
    asm volatile("s_waitcnt vmcnt(0)" ::: "memory");   // kt3 data fully landed
    __builtin_amdgcn_s_barrier();                      // also: Bs2 image free
    // early a-tile stages into S2/S3 (inside old Bs2 image) — fly under
    // kt3 compute + epilogue + hoist
    STG64(0, SBUF(2));
    STG64(1, SBUF(3));
    COMPUTE1(qUs);                                     // kt3
    asm volatile("s_waitcnt lgkmcnt(0)" ::: "memory"); // kt3 LDS reads returned
    __builtin_amdgcn_s_barrier();                      // (no vmcnt drain!)

    // write acc -> qUs (row-major 256 cols, swizzled 16B chunks)
    // C/D layout: col = lane&15, row = quad*4 + reg (verified mapping)
    #pragma unroll
    for (int i = 0; i < 4; ++i)
      #pragma unroll
      for (int r = 0; r < 4; ++r) {
        const int lr = wm * 64 + i * 16 + quad * 4 + r;
        #pragma unroll
        for (int j = 0; j < 4; ++j) {
          const int col = wn * 64 + j * 16 + m16;
          const int ch = (col >> 3) ^ (lr & 7);
          qUs[lr * 256 + ch * 8 + (col & 7)] = f2bf(acc[i][j][r]);
        }
      }
  }
  asm volatile("s_waitcnt lgkmcnt(0)" ::: "memory");   // epilogue writes visible
  __builtin_amdgcn_s_barrier();                        // (no vmcnt drain!)

  // ================= phase 2: 32 a-tiles (64 rows) vs register-resident qU =================
  // hoist qU A-fragments: invariant across all 32 tiles (aq[2][8] = 64 VGPRs)
  s8v aq[2][8];
  #pragma unroll
  for (int kq = 0; kq < 8; ++kq) {
    const int cs = ((kq * 4 + quad) ^ (m16 & 7)) * 8;
    aq[0][kq] = *(const s8v*)&qUs[(wr32 + m16) * 256 + cs];
    aq[1][kq] = *(const s8v*)&qUs[(wr32 + 16 + m16) * 256 + cs];
  }
  // all waves' qU reads DATA-RETURNED before the S0/S1 region is restaged
  asm volatile("s_waitcnt lgkmcnt(0)" ::: "memory");
  __builtin_amdgcn_s_barrier();
  STG64(2, SBUF(0));                                   // qU tile region now dead

  float rmx[2][4];
  #pragma unroll
  for (int i = 0; i < 2; ++i)
    #pragma unroll
    for (int r = 0; r < 4; ++r) rmx[i][r] = -3.4e38f;

#define CMP64(tb, buf) do {                                                    \
    f4v acc[2][2] = {};                                                        \
    _Pragma("unroll")                                                          \
    for (int kq_ = 0; kq_ < 8; ++kq_) {                                        \
      const int cs_ = ((kq_ * 4 + quad) ^ (m16 & 7)) * 8;                      \
      _Pragma("unroll")                                                        \
      for (int j_ = 0; j_ < 2; ++j_) {                                         \
        const s8v bv_ = *(const s8v*)&(buf)[(wc32 + j_ * 16 + m16) * 256 + cs_]; \
        acc[0][j_] = __builtin_amdgcn_mfma_f32_16x16x32_bf16(aq[0][kq_], bv_, acc[0][j_], 0, 0, 0); \
        acc[1][j_] = __builtin_amdgcn_mfma_f32_16x16x32_bf16(aq[1][kq_], bv_, acc[1][j_], 0, 0, 0); \
      }                                                                        \
    }                                                                          \
    _Pragma("unroll")                                                          \
    for (int i_ = 0; i_ < 2; ++i_)                                             \
      _Pragma("unroll")                                                        \
      for (int r_ = 0; r_ < 4; ++r_)                                           \
        rmx[i_][r_] = fmaxf(rmx[i_][r_], fmaxf(acc[i_][0][r_], acc[i_][1][r_])); \
    _Pragma("unroll")                                                          \
    for (int j_ = 0; j_ < 2; ++j_) {                                           \
      float v_ = fmaxf(fmaxf(acc[0][j_][0], acc[0][j_][1]),                    \
                       fmaxf(acc[0][j_][2], acc[0][j_][3]));                   \
      v_ = fmaxf(v_, fmaxf(fmaxf(acc[1][j_][0], acc[1][j_][1]),                \
                           fmaxf(acc[1][j_][2], acc[1][j_][3])));              \
      v_ = fmaxf(v_, __shfl_xor(v_, 16));                                      \
      v_ = fmaxf(v_, __shfl_xor(v_, 32));                                      \
      if (quad == 0)                                                           \
        atomicMax(&colLds[(tb) * 64 + wc32 + j_ * 16 + m16], encf(v_));        \
    }                                                                          \
  } while (0)

  // depth-3 ring pipeline: before compute(t), tiles t+1..t+3 staged (12 in
  // flight) -> vmcnt(8) proves tile t landed. stage(t+3) targets SBUF((t+1)&3)
  // = the buffer freed by compute(t-1) (tile t-1 uses (t+1)&3).
  #pragma unroll 1
  for (int t = 0; t < 30; ++t) {
    asm volatile("s_waitcnt vmcnt(8)" ::: "memory");   // tile t's 4/thread landed
    __builtin_amdgcn_s_barrier();                      // ...for ALL waves
    if (t <= 28) STG64(t + 3, SBUF((t + 1) & 3));
    CMP64(t, SBUF((t + 2) & 3));
    __builtin_amdgcn_s_barrier();                      // buf reads done -> restage-safe
  }
  asm volatile("s_waitcnt vmcnt(4)" ::: "memory");     // tile 30 landed
  __builtin_amdgcn_s_barrier();
  CMP64(30, SBUF(0));
  __builtin_amdgcn_s_barrier();
  asm volatile("s_waitcnt vmcnt(0)" ::: "memory");     // tile 31 landed
  __builtin_amdgcn_s_barrier();
  CMP64(31, SBUF(1));

  // ---- final row maxes: shuffle over m16, combine via LDS, store ----
  #pragma unroll
  for (int i = 0; i < 2; ++i)
    #pragma unroll
    for (int r = 0; r < 4; ++r) {
      float v = rmx[i][r];
      #pragma unroll
      for (int d2 = 1; d2 < 16; d2 <<= 1) v = fmaxf(v, __shfl_xor(v, d2));
      if (m16 == 0) atomicMax(&rowLds[wr32 + i * 16 + quad * 4 + r], encf(v));
    }
  __syncthreads();
  if (tid < 128)
    rowmax[(long)b * 2048 + tm * 128 + tid] = rowLds[tid];   // plain store (block owns rows)
  // ---- col maxes: one global atomic pass ----
  #pragma unroll
  for (int i = 0; i < 4; ++i)
    atomicMax(&colmax[(long)b * 2048 + i * 512 + tid], colLds[i * 512 + tid]);
}

// ---------- fused softmax + weighted sum (bf16 inputs, 16B/lane loads) ----------
__global__ void wsum_kernel(const uint4* __restrict__ qb, const uint4* __restrict__ ab,
                            const unsigned* __restrict__ rowmax, const unsigned* __restrict__ colmax,
                            float* __restrict__ out) {
  const int tid = threadIdx.x;
  const int chunk = blockIdx.x;
  const int b = blockIdx.y;
  const int z = blockIdx.z;
  const unsigned* e = z ? colmax : rowmax;
  const uint4* src = z ? ab : qb;

  __shared__ float sm[4];
  __shared__ float ss[4];
  __shared__ float wLds[128];
  __shared__ float red[256 * 8];   // 8 KB

  float x[8];
  float m = -3.4e38f;
  #pragma unroll
  for (int j = 0; j < 8; ++j) {
    x[j] = tanhf(decf(e[b * 2048 + j * 256 + tid]));
    m = fmaxf(m, x[j]);
  }
  #pragma unroll
  for (int d2 = 1; d2 < 64; d2 <<= 1) m = fmaxf(m, __shfl_xor(m, d2));
  if ((tid & 63) == 0) sm[tid >> 6] = m;
  __syncthreads();
  m = fmaxf(fmaxf(sm[0], sm[1]), fmaxf(sm[2], sm[3]));
  float s = 0.f;
  #pragma unroll
  for (int j = 0; j < 8; ++j) s += expf(x[j] - m);
  #pragma unroll
  for (int d2 = 1; d2 < 64; d2 <<= 1) s += __shfl_xor(s, d2);
  if ((tid & 63) == 0) ss[tid >> 6] = s;
  __syncthreads();
  const float inv = 1.f / (ss[0] + ss[1] + ss[2] + ss[3]);

  if (tid < 128) {
    float xv = tanhf(decf(e[b * 2048 + chunk * 128 + tid]));
    wLds[tid] = expf(xv - m) * inv;
  }
  __syncthreads();

  const int dg = tid & 31;
  const int rg = tid >> 5;       // 0..7, rows stride 8
  float acc[8] = {};
  const long rowbase = (long)b * 2048 + chunk * 128;
  for (int t = rg; t < 128; t += 8) {
    const float wgt = wLds[t];
    uint4 v = src[(rowbase + t) * 32 + dg];
    acc[0] += wgt * __uint_as_float(v.x << 16);
    acc[1] += wgt * __uint_as_float(v.x & 0xFFFF0000u);
    acc[2] += wgt * __uint_as_float(v.y << 16);
    acc[3] += wgt * __uint_as_float(v.y & 0xFFFF0000u);
    acc[4] += wgt * __uint_as_float(v.z << 16);
    acc[5] += wgt * __uint_as_float(v.z & 0xFFFF0000u);
    acc[6] += wgt * __uint_as_float(v.w << 16);
    acc[7] += wgt * __uint_as_float(v.w & 0xFFFF0000u);
  }
  #pragma unroll
  for (int k = 0; k < 8; ++k) red[tid * 8 + k] = acc[k];
  __syncthreads();
  if (tid < 32) {
    #pragma unroll
    for (int k = 0; k < 8; ++k) {
      float v = 0.f;
      #pragma unroll
      for (int g = 0; g < 8; ++g) v += red[((g << 5) | tid) * 8 + k];
      atomicAdd(&out[z * 4096 + b * 256 + tid * 8 + k], v);
    }
  }
}

// ---------- launch ----------
extern "C" void kernel_launch(void* const* d_in, const int* in_sizes, int n_in,
                              void* d_out, int out_size, void* d_ws, size_t ws_size,
                              hipStream_t stream) {
  const float* q = (const float*)d_in[0];
  const float* a = (const float*)d_in[1];
  const float* U = (const float*)d_in[2];
  float* out = (float*)d_out;

  char* w = (char*)d_ws;
  unsigned short* qb = (unsigned short*)w;                       // 16 MB
  unsigned short* ab = (unsigned short*)(w + (16ull << 20));     // 16 MB
  unsigned short* Ut = (unsigned short*)(w + (32ull << 20));     // 128 KB
  unsigned* rmax = (unsigned*)(w + (32ull << 20) + (128ull << 10));
  unsigned* cmax = rmax + 32768;

  // allow 139776 B dynamic LDS for the fused kernel (host-side, idempotent)
  constexpr int SMEM = 139776;
  hipFuncSetAttribute((const void*)fused_qu_smax,
                      hipFuncAttributeMaxDynamicSharedMemorySize, SMEM);

  // fused q/a bf16-cast + U transpose + rmax/cmax zero + out zero
  convert_kernel<<<8352, 256, 0, stream>>>((const float4*)q, (const float4*)a, U,
                                           (ushort4*)qb, (ushort4*)ab, Ut, rmax, out);

  // qU tile in LDS + S row/col maxes; grid (b, tm) -> XCD == b%8; 8 waves/block
  fused_qu_smax<<<dim3(16, 16), 512, SMEM, stream>>>(qb, Ut, ab, rmax, cmax);

  // fused softmax + weighted pooling (bf16, 16B/lane)
  wsum_kernel<<<dim3(16, 16, 2), 256, 0, stream>>>((const uint4*)qb, (const uint4*)ab,
                                                   rmax, cmax, out);
}